// Round 2
// baseline (323.208 us; speedup 1.0000x reference)
//
#include <hip/hip_runtime.h>

// ---- hash / bucket constants ----
#define HBITS 19
#define HSIZE (1u << HBITS)
#define HMASK (HSIZE - 1u)
#define EMPTY_KEY 0xFFFFFFFFu
#define SLOTS 8   // direct slots per voxel; overflow (P~1e-4) goes to chain

__device__ __forceinline__ unsigned hash_key(unsigned k) {
    return (k * 2654435761u) >> (32 - HBITS);
}

__device__ __forceinline__ unsigned pack_key(int4 c) {
    // c.x = batch (<4), c.y/z/w = xyz in [0,256)
    return ((unsigned)c.x << 24) | ((unsigned)c.y << 16) |
           ((unsigned)c.z << 8) | (unsigned)c.w;
}

// Kernel A: insert voxel keys; htab[h] = (key, min original index).
__global__ __launch_bounds__(256)
void build_hash(const int4* __restrict__ tgt_coords, int M,
                uint2* __restrict__ htab) {
    int v = blockIdx.x * blockDim.x + threadIdx.x;
    if (v >= M) return;
    unsigned key = pack_key(tgt_coords[v]);
    unsigned h = hash_key(key);
    while (true) {
        unsigned prev = atomicCAS(&htab[h].x, EMPTY_KEY, key);
        if (prev == EMPTY_KEY || prev == key) {
            atomicMin(&htab[h].y, (unsigned)v);   // canonical = min index
            break;
        }
        h = (h + 1u) & HMASK;
    }
}

// Kernel A2: resolve canonical voxel index once per voxel (200k probes)
// so fill_slots does a single 4B gather per point instead of a coord
// gather + probe chain (moves probe work from 400k points to 200k voxels).
__global__ __launch_bounds__(256)
void canonize(const int4* __restrict__ tgt_coords,
              const uint2* __restrict__ htab, int M,
              int* __restrict__ canon) {
    int v = blockIdx.x * blockDim.x + threadIdx.x;
    if (v >= M) return;
    unsigned key = pack_key(tgt_coords[v]);
    unsigned h = hash_key(key);
    uint2 e = htab[h];
    while (e.x != key) { h = (h + 1u) & HMASK; e = htab[h]; }
    canon[v] = (int)e.y;
}

// Kernel B: each point claims a bucket slot in its canonical voxel.
// cnt[] init = -1 (0xFF memset) so atomicAdd+1 gives slot 0,1,...
__global__ __launch_bounds__(256)
void fill_slots(const int* __restrict__ pts_idx,
                const int* __restrict__ canon,
                int BN,
                int* __restrict__ cnt,      // (M) init -1
                int* __restrict__ slotbuf,  // (M*SLOTS) no init needed
                int* __restrict__ ohead,    // (M) init -1
                int* __restrict__ nxt) {    // (BN) no init needed
    int p = blockIdx.x * blockDim.x + threadIdx.x;
    if (p >= BN) return;
    int c = canon[pts_idx[p]];
    int idx = atomicAdd(&cnt[c], 1) + 1;
    if (idx < SLOTS) slotbuf[c * SLOTS + idx] = p;
    else             nxt[p] = atomicExch(&ohead[c], p);   // rare
}

// Kernel E v2: FUSED gather-mean + 96->32 GEMV, scalar-W edition.
//  - 128 voxels / 256-thread block. LDS x-rows stride 98 floats (even ->
//    float2-aligned; bank stride 2 -> 2-way conflicts = free).
//  - phase 1: 16 passes of the proven 32-lane/voxel gather (4 VMEM
//    wave-instrs per voxel); x = [tgt(32)|mean(64)] written to LDS only.
//  - phase 2: 2 threads/voxel, 16 out-channels each, acc[16] in VGPRs.
//    ocb forced wave-uniform via readfirstlane -> W and bias come in as
//    s_load broadcasts (scalar K$ path, zero VMEM-port pressure — the
//    round-1 kernel burned ~60us of L1-port issue on per-lane W loads).
//    x read as per-lane ds_read_b64 (2-way bank alias, free).
#define VOXB 128
#define XSTR 98
__global__ __launch_bounds__(256)
void gather_fuse(const float2* __restrict__ pf2,   // (BN,64) as (BN,32) float2
                 const float* __restrict__ tgtf,   // (M,32)
                 const int* __restrict__ cnt,
                 const int4* __restrict__ slot4,   // slotbuf as (M,2) int4
                 const int* __restrict__ ohead,
                 const int* __restrict__ nxt,
                 const float* __restrict__ W,      // (96,32)
                 const float* __restrict__ bias,   // (32,)
                 int M,
                 float* __restrict__ out) {        // (M,32)
    __shared__ __align__(16) float xs[VOXB][XSTR];   // 50176 B -> 3 blocks/CU

    int t = threadIdx.x;
    int grp = t >> 5;
    int g   = t & 31;
    int vbase = blockIdx.x * VOXB;

    // ---- phase 1: gather-mean into LDS, 8 voxels per pass ----
    for (int pp = 0; pp < VOXB / 8; ++pp) {
        int vb = pp * 8 + grp;
        int v  = vbase + vb;
        if (v < M) {
            int n = cnt[v] + 1;
            int4 sa = make_int4(0, 0, 0, 0), sb = make_int4(0, 0, 0, 0);
            if (n > 0) sa = slot4[(size_t)v * 2];
            if (n > 4) sb = slot4[(size_t)v * 2 + 1];
            float2 f0 = {0,0}, f1 = {0,0}, f2 = {0,0}, f3 = {0,0};
            float2 f4 = {0,0}, f5 = {0,0}, f6 = {0,0}, f7 = {0,0};
            if (n > 0) f0 = pf2[(size_t)sa.x * 32 + g];
            if (n > 1) f1 = pf2[(size_t)sa.y * 32 + g];
            if (n > 2) f2 = pf2[(size_t)sa.z * 32 + g];
            if (n > 3) f3 = pf2[(size_t)sa.w * 32 + g];
            if (n > 4) f4 = pf2[(size_t)sb.x * 32 + g];
            if (n > 5) f5 = pf2[(size_t)sb.y * 32 + g];
            if (n > 6) f6 = pf2[(size_t)sb.z * 32 + g];
            if (n > 7) f7 = pf2[(size_t)sb.w * 32 + g];
            float sx = ((f0.x + f1.x) + (f2.x + f3.x)) + ((f4.x + f5.x) + (f6.x + f7.x));
            float sy = ((f0.y + f1.y) + (f2.y + f3.y)) + ((f4.y + f5.y) + (f6.y + f7.y));
            if (n > SLOTS) {   // extremely rare overflow chain
                int p = ohead[v];
                while (p >= 0) {
                    float2 f = pf2[(size_t)p * 32 + g];
                    sx += f.x; sy += f.y;
                    p = nxt[p];
                }
            }
            float inv = 1.0f / fmaxf((float)n, 1.0f);
            xs[vb][g] = tgtf[(size_t)v * 32 + g];                    // x[0..31]
            *reinterpret_cast<float2*>(&xs[vb][32 + 2 * g]) =
                make_float2(sx * inv, sy * inv);                     // x[32..95]
        }
    }

    __syncthreads();

    // ---- phase 2: GEMV, 2 threads per voxel, scalar W ----
    int vb2 = t & (VOXB - 1);
    int ocb = __builtin_amdgcn_readfirstlane((t >> 7) << 4);  // 0 or 16, wave-uniform
    int v2  = vbase + vb2;
    if (v2 < M) {
        float acc[16];
#pragma unroll
        for (int j = 0; j < 16; ++j) acc[j] = bias[ocb + j];

#pragma unroll 4
        for (int k4 = 0; k4 < 24; ++k4) {
            float2 xa = *reinterpret_cast<const float2*>(&xs[vb2][k4 * 4]);
            float2 xb = *reinterpret_cast<const float2*>(&xs[vb2][k4 * 4 + 2]);
            const float* w0 = W + (k4 * 4 + 0) * 32 + ocb;
            const float* w1 = W + (k4 * 4 + 1) * 32 + ocb;
            const float* w2 = W + (k4 * 4 + 2) * 32 + ocb;
            const float* w3 = W + (k4 * 4 + 3) * 32 + ocb;
#pragma unroll
            for (int j = 0; j < 16; ++j) {
                acc[j] = fmaf(xa.x, w0[j], acc[j]);
                acc[j] = fmaf(xa.y, w1[j], acc[j]);
                acc[j] = fmaf(xb.x, w2[j], acc[j]);
                acc[j] = fmaf(xb.y, w3[j], acc[j]);
            }
        }

        float4* o = reinterpret_cast<float4*>(out + (size_t)v2 * 32 + ocb);
#pragma unroll
        for (int q = 0; q < 4; ++q)
            o[q] = make_float4(acc[4 * q], acc[4 * q + 1],
                               acc[4 * q + 2], acc[4 * q + 3]);
    }
}

extern "C" void kernel_launch(void* const* d_in, const int* in_sizes, int n_in,
                              void* d_out, int out_size, void* d_ws, size_t ws_size,
                              hipStream_t stream) {
    const float* pfeat      = (const float*)d_in[0];  // (BN,64)
    const float* tgt_feats  = (const float*)d_in[1];  // (M,32)
    const float* W_fuse     = (const float*)d_in[2];  // (96,32)
    const float* b_fuse     = (const float*)d_in[3];  // (32,)
    const int*   tgt_coords = (const int*)d_in[4];    // (M,4)
    const int*   pts_idx    = (const int*)d_in[5];    // (BN,)
    float* out = (float*)d_out;                       // (M,32)

    const int M  = in_sizes[4] / 4;
    const int BN = in_sizes[5];

    // workspace: [htab 4MB | cnt M | ohead M]  <- single 0xFF memset region
    //            [canon M | slotbuf M*8 | nxt BN] <- write-before-read
    char* ws = (char*)d_ws;
    uint2* htab    = (uint2*)ws;
    size_t off = (size_t)HSIZE * 8;
    int*   cnt     = (int*)(ws + off);              off += (size_t)M * 4;
    int*   ohead   = (int*)(ws + off);              off += (size_t)M * 4;
    int*   canon   = (int*)(ws + off);              off += (size_t)M * 4;
    int*   slotbuf = (int*)(ws + off);              off += (size_t)M * SLOTS * 4;
    int*   nxt     = (int*)(ws + off);

    size_t ff_bytes = (size_t)HSIZE * 8 + (size_t)M * 8;  // htab + cnt + ohead
    hipMemsetAsync(htab, 0xFF, ff_bytes, stream);  // EMPTY_KEY / UINT_MAX / -1

    const int TB = 256;
    build_hash<<<(M + TB - 1) / TB, TB, 0, stream>>>(
        (const int4*)tgt_coords, M, htab);
    canonize<<<(M + TB - 1) / TB, TB, 0, stream>>>(
        (const int4*)tgt_coords, htab, M, canon);
    fill_slots<<<(BN + TB - 1) / TB, TB, 0, stream>>>(
        pts_idx, canon, BN, cnt, slotbuf, ohead, nxt);
    gather_fuse<<<(M + VOXB - 1) / VOXB, TB, 0, stream>>>(
        (const float2*)pfeat, tgt_feats, cnt, (const int4*)slotbuf, ohead, nxt,
        W_fuse, b_fuse, M, out);
}

// Round 3
// 269.368 us; speedup vs baseline: 1.1999x; 1.1999x over previous
//
#include <hip/hip_runtime.h>

// ---- hash / bucket constants ----
#define HBITS 19
#define HSIZE (1u << HBITS)
#define HMASK (HSIZE - 1u)
#define EMPTY_KEY 0xFFFFFFFFu
#define SLOTS 8   // direct slots per voxel; overflow (P~1e-4) goes to chain

__device__ __forceinline__ unsigned hash_key(unsigned k) {
    return (k * 2654435761u) >> (32 - HBITS);
}

__device__ __forceinline__ unsigned pack_key(int4 c) {
    // c.x = batch (<4), c.y/z/w = xyz in [0,256)
    return ((unsigned)c.x << 24) | ((unsigned)c.y << 16) |
           ((unsigned)c.z << 8) | (unsigned)c.w;
}

// Kernel A: insert voxel keys; htab[h] = (key, min original index).
__global__ __launch_bounds__(256)
void build_hash(const int4* __restrict__ tgt_coords, int M,
                uint2* __restrict__ htab) {
    int v = blockIdx.x * blockDim.x + threadIdx.x;
    if (v >= M) return;
    unsigned key = pack_key(tgt_coords[v]);
    unsigned h = hash_key(key);
    while (true) {
        unsigned prev = atomicCAS(&htab[h].x, EMPTY_KEY, key);
        if (prev == EMPTY_KEY || prev == key) {
            atomicMin(&htab[h].y, (unsigned)v);   // canonical = min index
            break;
        }
        h = (h + 1u) & HMASK;
    }
}

// Kernel A2: resolve canonical voxel index once per voxel.
__global__ __launch_bounds__(256)
void canonize(const int4* __restrict__ tgt_coords,
              const uint2* __restrict__ htab, int M,
              int* __restrict__ canon) {
    int v = blockIdx.x * blockDim.x + threadIdx.x;
    if (v >= M) return;
    unsigned key = pack_key(tgt_coords[v]);
    unsigned h = hash_key(key);
    uint2 e = htab[h];
    while (e.x != key) { h = (h + 1u) & HMASK; e = htab[h]; }
    canon[v] = (int)e.y;
}

// Kernel B: each point claims a bucket slot in its canonical voxel.
__global__ __launch_bounds__(256)
void fill_slots(const int* __restrict__ pts_idx,
                const int* __restrict__ canon,
                int BN,
                int* __restrict__ cnt,      // (M) init -1
                int* __restrict__ slotbuf,  // (M*SLOTS) no init needed
                int* __restrict__ ohead,    // (M) init -1
                int* __restrict__ nxt) {    // (BN) no init needed
    int p = blockIdx.x * blockDim.x + threadIdx.x;
    if (p >= BN) return;
    int c = canon[pts_idx[p]];
    int idx = atomicAdd(&cnt[c], 1) + 1;
    if (idx < SLOTS) slotbuf[c * SLOTS + idx] = p;
    else             nxt[p] = atomicExch(&ohead[c], p);   // rare
}

// Kernel E v3: FUSED gather-mean + 96->32 GEMV.
// Fixes round-2's occupancy collapse (50KB LDS -> 3 blocks/CU -> 26% occ,
// phase-1 latency chain exposed, 134us @ 8.7% HBM):
//  - VOXB=64: LDS ~27.4KB, __launch_bounds__(256,4) -> 4 blocks/CU (16
//    waves), 2x the resident waves; ~64KB of gather bytes in flight per CU.
//  - slot metadata (cnt + slot4) pre-staged to LDS with 2 coalesced
//    block-wide loads: per-pass chain is LDS-read -> pfeat loads (1 global
//    hop instead of 3), and all passes' indices are ready at once so the
//    compiler can overlap passes.
//  - phase 2: lane = voxel, wave = 8-channel block (ocb wave-uniform via
//    readfirstlane -> W/bias are s_load broadcasts, zero VMEM pressure).
#define VOXB 64
#define XSTR 98   // even (float2-aligned); %32 banks=2 -> benign aliasing
__global__ __launch_bounds__(256, 4)
void gather_fuse(const float2* __restrict__ pf2,   // (BN,64) as (BN,32) float2
                 const float* __restrict__ tgtf,   // (M,32)
                 const int* __restrict__ cnt,
                 const int4* __restrict__ slot4,   // slotbuf as (M,2) int4
                 const int* __restrict__ ohead,
                 const int* __restrict__ nxt,
                 const float* __restrict__ W,      // (96,32)
                 const float* __restrict__ bias,   // (32,)
                 int M,
                 float* __restrict__ out) {        // (M,32)
    __shared__ __align__(16) float xs[VOXB][XSTR];   // 25088 B
    __shared__ int scnt[VOXB];                       // 256 B
    __shared__ __align__(16) int4 sslot[VOXB * 2];   // 2048 B

    int t = threadIdx.x;
    int vbase = blockIdx.x * VOXB;

    // ---- pre-phase: coalesced slot-metadata staging ----
    if (t < VOXB) {
        int v = vbase + t;
        scnt[t] = (v < M) ? cnt[v] : -1;
    }
    if (t < VOXB * 2) {
        int j = vbase * 2 + t;
        sslot[t] = (j < M * 2) ? slot4[j] : make_int4(0, 0, 0, 0);
    }
    __syncthreads();

    int grp = t >> 5;
    int g   = t & 31;

    // ---- phase 1: gather-mean into LDS, 8 voxels per pass ----
    for (int pp = 0; pp < VOXB / 8; ++pp) {
        int vb = pp * 8 + grp;
        int v  = vbase + vb;
        if (v < M) {
            int n = scnt[vb] + 1;
            int4 sa = sslot[vb * 2];
            int4 sb = sslot[vb * 2 + 1];
            float2 f0 = {0,0}, f1 = {0,0}, f2 = {0,0}, f3 = {0,0};
            float2 f4 = {0,0}, f5 = {0,0}, f6 = {0,0}, f7 = {0,0};
            if (n > 0) f0 = pf2[(size_t)sa.x * 32 + g];
            if (n > 1) f1 = pf2[(size_t)sa.y * 32 + g];
            if (n > 2) f2 = pf2[(size_t)sa.z * 32 + g];
            if (n > 3) f3 = pf2[(size_t)sa.w * 32 + g];
            if (n > 4) f4 = pf2[(size_t)sb.x * 32 + g];
            if (n > 5) f5 = pf2[(size_t)sb.y * 32 + g];
            if (n > 6) f6 = pf2[(size_t)sb.z * 32 + g];
            if (n > 7) f7 = pf2[(size_t)sb.w * 32 + g];
            float sx = ((f0.x + f1.x) + (f2.x + f3.x)) + ((f4.x + f5.x) + (f6.x + f7.x));
            float sy = ((f0.y + f1.y) + (f2.y + f3.y)) + ((f4.y + f5.y) + (f6.y + f7.y));
            if (n > SLOTS) {   // extremely rare overflow chain
                int p = ohead[v];
                while (p >= 0) {
                    float2 f = pf2[(size_t)p * 32 + g];
                    sx += f.x; sy += f.y;
                    p = nxt[p];
                }
            }
            float inv = 1.0f / fmaxf((float)n, 1.0f);
            xs[vb][g] = tgtf[(size_t)v * 32 + g];                    // x[0..31]
            *reinterpret_cast<float2*>(&xs[vb][32 + 2 * g]) =
                make_float2(sx * inv, sy * inv);                     // x[32..95]
        }
    }

    __syncthreads();

    // ---- phase 2: GEMV, lane = voxel, wave = 8-channel block ----
    int vb2 = t & (VOXB - 1);
    int ocb = __builtin_amdgcn_readfirstlane((t >> 6) << 3);  // 0/8/16/24
    int v2  = vbase + vb2;
    if (v2 < M) {
        float acc[8];
#pragma unroll
        for (int j = 0; j < 8; ++j) acc[j] = bias[ocb + j];

#pragma unroll 4
        for (int k4 = 0; k4 < 24; ++k4) {
            float2 xa = *reinterpret_cast<const float2*>(&xs[vb2][k4 * 4]);
            float2 xb = *reinterpret_cast<const float2*>(&xs[vb2][k4 * 4 + 2]);
            const float* w0 = W + (k4 * 4 + 0) * 32 + ocb;
            const float* w1 = W + (k4 * 4 + 1) * 32 + ocb;
            const float* w2 = W + (k4 * 4 + 2) * 32 + ocb;
            const float* w3 = W + (k4 * 4 + 3) * 32 + ocb;
#pragma unroll
            for (int j = 0; j < 8; ++j) {
                acc[j] = fmaf(xa.x, w0[j], acc[j]);
                acc[j] = fmaf(xa.y, w1[j], acc[j]);
                acc[j] = fmaf(xb.x, w2[j], acc[j]);
                acc[j] = fmaf(xb.y, w3[j], acc[j]);
            }
        }

        float4* o = reinterpret_cast<float4*>(out + (size_t)v2 * 32 + ocb);
        o[0] = make_float4(acc[0], acc[1], acc[2], acc[3]);
        o[1] = make_float4(acc[4], acc[5], acc[6], acc[7]);
    }
}

extern "C" void kernel_launch(void* const* d_in, const int* in_sizes, int n_in,
                              void* d_out, int out_size, void* d_ws, size_t ws_size,
                              hipStream_t stream) {
    const float* pfeat      = (const float*)d_in[0];  // (BN,64)
    const float* tgt_feats  = (const float*)d_in[1];  // (M,32)
    const float* W_fuse     = (const float*)d_in[2];  // (96,32)
    const float* b_fuse     = (const float*)d_in[3];  // (32,)
    const int*   tgt_coords = (const int*)d_in[4];    // (M,4)
    const int*   pts_idx    = (const int*)d_in[5];    // (BN,)
    float* out = (float*)d_out;                       // (M,32)

    const int M  = in_sizes[4] / 4;
    const int BN = in_sizes[5];

    // workspace: [htab 4MB | cnt M | ohead M]  <- single 0xFF memset region
    //            [canon M | slotbuf M*8 | nxt BN] <- write-before-read
    char* ws = (char*)d_ws;
    uint2* htab    = (uint2*)ws;
    size_t off = (size_t)HSIZE * 8;
    int*   cnt     = (int*)(ws + off);              off += (size_t)M * 4;
    int*   ohead   = (int*)(ws + off);              off += (size_t)M * 4;
    int*   canon   = (int*)(ws + off);              off += (size_t)M * 4;
    int*   slotbuf = (int*)(ws + off);              off += (size_t)M * SLOTS * 4;
    int*   nxt     = (int*)(ws + off);

    size_t ff_bytes = (size_t)HSIZE * 8 + (size_t)M * 8;  // htab + cnt + ohead
    hipMemsetAsync(htab, 0xFF, ff_bytes, stream);  // EMPTY_KEY / UINT_MAX / -1

    const int TB = 256;
    build_hash<<<(M + TB - 1) / TB, TB, 0, stream>>>(
        (const int4*)tgt_coords, M, htab);
    canonize<<<(M + TB - 1) / TB, TB, 0, stream>>>(
        (const int4*)tgt_coords, htab, M, canon);
    fill_slots<<<(BN + TB - 1) / TB, TB, 0, stream>>>(
        pts_idx, canon, BN, cnt, slotbuf, ohead, nxt);
    gather_fuse<<<(M + VOXB - 1) / VOXB, TB, 0, stream>>>(
        (const float2*)pfeat, tgt_feats, cnt, (const int4*)slotbuf, ohead, nxt,
        W_fuse, b_fuse, M, out);
}